// Round 16
// baseline (279.742 us; speedup 1.0000x reference)
//
#include <hip/hip_runtime.h>
#include <hip/hip_bf16.h>
#include <hip/hip_fp16.h>
#include <math.h>

#define XW 4099
#define DSD 3
#define BSZ 8192
#define KP1 1696   // fc1 K padded: 1693 -> 1696 (multiple of 32, 16B-aligned rows)

typedef __attribute__((ext_vector_type(8))) _Float16 f16x8;
typedef __attribute__((ext_vector_type(4))) float    f32x4;

static __device__ __forceinline__ short f2h(float f) {
    union { _Float16 h; short s; } u;
    u.h = (_Float16)f;
    return u.s;
}

// ---------------------------------------------------------------------------
// Kernel 0: ALL weight conversions in one launch.
// ---------------------------------------------------------------------------
#define C0 (512 * KP1)
#define C1 (C0 + 256 * 512)
#define C2 (C1 + 128 * 256)
#define C3 (C2 + 64 * 128)
__global__ __launch_bounds__(256) void cvt_all(
    const float* __restrict__ w1s, short* __restrict__ w1d,
    const float* __restrict__ w2s, short* __restrict__ w2d,
    const float* __restrict__ w3s, short* __restrict__ w3d,
    const float* __restrict__ w4s, short* __restrict__ w4d)
{
    const int i = blockIdx.x * 256 + threadIdx.x;
    if (i < C0) {
        const int n = i / KP1, k = i % KP1;
        w1d[i] = (k < 1693) ? f2h(w1s[(size_t)n * 1693 + k]) : (short)0;
    } else if (i < C1) {
        const int j = i - C0; w2d[j] = f2h(w2s[j]);
    } else if (i < C2) {
        const int j = i - C1; w3d[j] = f2h(w3s[j]);
    } else if (i < C3) {
        const int j = i - C2; w4d[j] = f2h(w4s[j]);
    }
}

// ---------------------------------------------------------------------------
// Kernel 1: fused conv — BOTH convs on MFMA.
// conv1 implicit GEMM: M = 900 pool-windows (window-packed: lane's 4 C-regs
// = one 2x2 window), N = 5 ch (pad 16), K'' = ky*8+kx = 64 (kx 5..7 and
// ky 5..7 zero-weighted). A-fragment = 8 consecutive f16 pixels; per-lane
// even base col via dual image copies (imgB = 1-col-shifted) -> 4x aligned
// ds_read_b32. conv2: validated r15 form.
// ---------------------------------------------------------------------------
__global__ __launch_bounds__(256, 4) void conv_fused(
    const float* __restrict__ x,
    const float* __restrict__ w1, const float* __restrict__ b1,
    const float* __restrict__ w2, const float* __restrict__ b2,
    short* __restrict__ act1)
{
    // imgA/imgB f16 [68][68] each (9248 B each); w2f aliases after conv1
    __shared__ __align__(16) char smem0[2 * 68 * 68 * 2];   // 18496 B
    _Float16 (*imgA)[68] = (_Float16(*)[68])smem0;
    _Float16 (*imgB)[68] = (_Float16(*)[68])(smem0 + 9248);
    _Float16 (*w2f)[232] = (_Float16(*)[232])smem0;

    __shared__ __align__(16) _Float16 h1[30][30][8];   // 14400 B; y-stride 480 B
    __shared__ __align__(16) _Float16 w1f[16][72];     // conv1 B-matrix, row 144 B
    __shared__ float cb1s[16];
    __shared__ float cb2s[16];
    __shared__ __align__(16) int kofft[28];            // conv2 kpos -> byte offset

    const int b = blockIdx.x;
    const int t = threadIdx.x;

    // ---- phase 0: zero imgA/imgB + h1; build w1f and small tables
    {
        uint4* z = (uint4*)smem0;
        const uint4 z4 = {0u, 0u, 0u, 0u};
        #pragma unroll
        for (int i = 0; i < 5; ++i) {
            const int idx = t + 256 * i;
            if (idx < 1156) z[idx] = z4;
        }
        uint4* h1z = (uint4*)&h1[0][0][0];
        #pragma unroll
        for (int i = 0; i < 4; ++i) {
            const int idx = t + 256 * i;
            if (idx < 900) h1z[idx] = z4;
        }
    }
    if (t < 128) {   // w1f[ch][k]: ky=(k>>5)*4+((k>>3)&3), kx=k&7
        const int ch = t >> 3, k0 = (t & 7) * 8;
        f16x8 cell;
        #pragma unroll
        for (int j = 0; j < 8; ++j) {
            const int k = k0 + j;
            const int ky = (k >> 5) * 4 + ((k >> 3) & 3);
            const int kx = k & 7;
            cell[j] = (ch < 5 && ky < 5 && kx < 5)
                    ? (_Float16)w1[ch * 25 + ky * 5 + kx] : (_Float16)0.f;
        }
        *(f16x8*)&w1f[ch][k0] = cell;
    }
    if (t >= 128 && t < 144) cb1s[t - 128] = (t - 128 < 5) ? b1[t - 128] : 0.f;
    if (t >= 160 && t < 176) cb2s[t - 160] = (t - 160 < 10) ? b2[t - 160] : 0.f;
    if (t >= 192 && t < 220) {
        const int p = t - 192;
        kofft[p] = (p < 25) ? (p / 5) * 480 + (p % 5) * 16 : 0;
    }
    __syncthreads();

    // ---- stage image: f32 -> f16 dual write (imgB[c] = v(c+1))
    const float* xr = x + (size_t)b * XW + DSD;
    #pragma unroll
    for (int i = 0; i < 16; ++i) {
        const int idx = t + 256 * i;
        const int yy = idx >> 6, xx = idx & 63;
        const _Float16 v = (_Float16)xr[idx];
        imgA[yy][xx] = v;
        if (xx > 0) imgB[yy][xx - 1] = v;
    }
    __syncthreads();

    // ---- conv1 via MFMA implicit GEMM + in-lane 2x2 pool + relu -> h1
    {
        const int lane = t & 63, wv_ = t >> 6;
        const int lr = lane & 15, kg = lane >> 4;
        const int wa = lr >> 2;                 // A-row's window within tile
        const int dy = lr & 1, dx = (lr >> 1) & 1;
        const f16x8 bf0 = *(const f16x8*)&w1f[lr][kg * 8];
        const f16x8 bf1 = *(const f16x8*)&w1f[lr][32 + kg * 8];
        const char* base0 = dx ? (const char*)&imgB[0][0] : (const char*)&imgA[0][0];
        const float bias1 = cb1s[lr];
        const int r0 = kg * 136;                // s=0: ky = kg
        const int r1 = (4 + kg) * 136;          // s=1: ky = 4+kg

        #pragma unroll 1
        for (int tt = wv_; tt < 225; tt += 4) {
            // A-row window (input side)
            const int w_A = tt * 4 + wa;                 // 0..899
            const int wyA = (w_A * 2185) >> 16;          // /30
            const int wxA = w_A - wyA * 30;
            const char* pb = base0 + (2 * wyA + dy) * 136 + wxA * 4;
            union { f16x8 v; unsigned u[4]; } A0, A1;
            #pragma unroll
            for (int j = 0; j < 4; ++j) A0.u[j] = *(const unsigned*)(pb + r0 + 4 * j);
            #pragma unroll
            for (int j = 0; j < 4; ++j) A1.u[j] = *(const unsigned*)(pb + r1 + 4 * j);
            f32x4 acc = {0.f, 0.f, 0.f, 0.f};
            acc = __builtin_amdgcn_mfma_f32_16x16x32_f16(A0.v, bf0, acc, 0, 0, 0);
            acc = __builtin_amdgcn_mfma_f32_16x16x32_f16(A1.v, bf1, acc, 0, 0, 0);
            // C window (output side): rows kg*4+q = window tt*4+kg, ch = lr
            if (lr < 5) {
                const int w_C = tt * 4 + kg;
                const int wyC = (w_C * 2185) >> 16;
                const int wxC = w_C - wyC * 30;
                const float m = fmaxf(fmaxf(acc[0], acc[1]), fmaxf(acc[2], acc[3]));
                h1[wyC][wxC][lr] = (_Float16)fmaxf(m + bias1, 0.f);
            }
        }
    }
    __syncthreads();

    // ---- build w2f over the dead img region: 448 cells, 256 threads
    for (int i = t; i < 448; i += 256) {
        const int wc = i / 28, wp = i % 28;
        f16x8 cell;
        #pragma unroll
        for (int ic = 0; ic < 8; ++ic) cell[ic] = (_Float16)0.f;
        if (wc < 10 && wp < 25) {
            #pragma unroll
            for (int ic = 0; ic < 5; ++ic)
                cell[ic] = (_Float16)w2[(wc * 5 + ic) * 25 + wp];
        }
        *(f16x8*)&w2f[wc][wp * 8] = cell;
    }
    __syncthreads();

    // ---- conv2 via MFMA implicit GEMM, wide b128 A-fragments (r15 form)
    short* outr = act1 + (size_t)b * KP1;
    {
        const int wv_ = t >> 6, lane = t & 63;
        const int lr = lane & 15, kg = lane >> 4;
        const float bias2 = cb2s[lr];
        const int qa = lr & 3;
        const int wa_off = lr >> 2;

        int bases[11];
        #pragma unroll
        for (int u = 0; u < 11; ++u) {
            const int tt = u * 4 + wv_;                  // 0..43
            int w_A = tt * 4 + wa_off;                   // 0..175
            w_A = (w_A < 169) ? w_A : 168;               // clamp pad rows
            const int Y = (w_A * 5042) >> 16;            // /13
            const int X = w_A - Y * 13;
            bases[u] = (2 * Y + (qa & 1)) * 480 + (2 * X + (qa >> 1)) * 16;
        }

        f32x4 acc[11];
        #pragma unroll
        for (int u = 0; u < 11; ++u) acc[u] = (f32x4){0.f, 0.f, 0.f, 0.f};

        const char* h1p = (const char*)&h1[0][0][0];

        #pragma unroll 1
        for (int s = 0; s < 7; ++s) {
            const int koffp = kofft[s * 4 + kg];
            const f16x8 bfs = *(const f16x8*)&w2f[lr][s * 32 + kg * 8];
            #pragma unroll
            for (int u = 0; u < 11; ++u) {
                const f16x8 af = *(const f16x8*)(h1p + (bases[u] + koffp));
                acc[u] = __builtin_amdgcn_mfma_f32_16x16x32_f16(af, bfs, acc[u], 0, 0, 0);
            }
        }

        #pragma unroll
        for (int u = 0; u < 11; ++u) {
            const int tt = u * 4 + wv_;
            const int w_C = tt * 4 + kg;
            if (lr < 10 && w_C < 169) {
                const float m = fmaxf(fmaxf(acc[u][0], acc[u][1]), fmaxf(acc[u][2], acc[u][3]));
                outr[lr * 169 + w_C] = f2h(fmaxf(m + bias2, 0.f));
            }
        }
    }
    if (t < DSD)           outr[1690 + t] = f2h(x[(size_t)b * XW + t]);
    if (t >= DSD && t < 6) outr[1690 + t] = 0;   // zero pad 1693..1695
}

// ---------------------------------------------------------------------------
// Kernel 2: MFMA fp16 GEMM, 64x64 tile, BK=32 (r12-validated form)
// ---------------------------------------------------------------------------
template <int RELU, int OUTH>
__global__ __launch_bounds__(256) void mfma_fc(
    const short* __restrict__ A, const short* __restrict__ W,
    const float* __restrict__ bias, void* __restrict__ Cout,
    int N, int Kp)
{
    __shared__ __align__(16) short As[64][40];
    __shared__ __align__(16) short Ws[64][40];

    const int tid  = threadIdx.x;
    const int m0   = blockIdx.y * 64;
    const int n0   = blockIdx.x * 64;
    const int wv   = tid >> 6, lane = tid & 63;
    const int rm   = (wv >> 1) * 32, rn = (wv & 1) * 32;
    const int lr   = lane & 15, kg = lane >> 4;
    const int sr   = tid >> 2, sc = (tid & 3) * 8;

    f32x4 acc[2][2];
    #pragma unroll
    for (int i = 0; i < 2; ++i)
        #pragma unroll
        for (int j = 0; j < 2; ++j)
            #pragma unroll
            for (int q = 0; q < 4; ++q) acc[i][j][q] = 0.f;

    for (int k0 = 0; k0 < Kp; k0 += 32) {
        *(uint4*)&As[sr][sc] = *(const uint4*)&A[(size_t)(m0 + sr) * Kp + k0 + sc];
        *(uint4*)&Ws[sr][sc] = *(const uint4*)&W[(size_t)(n0 + sr) * Kp + k0 + sc];
        __syncthreads();
        f16x8 aF[2], bF[2];
        #pragma unroll
        for (int mi = 0; mi < 2; ++mi) aF[mi] = *(const f16x8*)&As[rm + mi * 16 + lr][kg * 8];
        #pragma unroll
        for (int nj = 0; nj < 2; ++nj) bF[nj] = *(const f16x8*)&Ws[rn + nj * 16 + lr][kg * 8];
        #pragma unroll
        for (int mi = 0; mi < 2; ++mi)
            #pragma unroll
            for (int nj = 0; nj < 2; ++nj)
                acc[mi][nj] = __builtin_amdgcn_mfma_f32_16x16x32_f16(
                    aF[mi], bF[nj], acc[mi][nj], 0, 0, 0);
        __syncthreads();
    }

    #pragma unroll
    for (int mi = 0; mi < 2; ++mi)
        #pragma unroll
        for (int nj = 0; nj < 2; ++nj) {
            const int col  = n0 + rn + nj * 16 + lr;
            const int rowb = m0 + rm + mi * 16 + kg * 4;
            const float bv = bias[col];
            #pragma unroll
            for (int q = 0; q < 4; ++q) {
                float v = acc[mi][nj][q] + bv;
                if (RELU) v = fmaxf(v, 0.f);
                if (OUTH) ((short*)Cout)[(size_t)(rowb + q) * N + col] = f2h(v);
                else      ((float*)Cout)[(size_t)(rowb + q) * N + col] = v;
            }
        }
}

// ---------------------------------------------------------------------------
// Kernel 4: fc5 + softmax + expert combine -> out[B,3]
// ---------------------------------------------------------------------------
__global__ __launch_bounds__(256) void head_kernel(
    const float* __restrict__ act5, const float* __restrict__ w5,
    const float* __restrict__ b5, const float* __restrict__ Bm,
    const float* __restrict__ Cm, const float* __restrict__ x,
    const float* __restrict__ x_tar, float* __restrict__ out)
{
    __shared__ float sw[16 * 64];
    __shared__ float sb[16];
    __shared__ float sA[16 * 9];
    __shared__ float st[3];
    const int t = threadIdx.x;
    for (int i = t; i < 1024; i += 256) sw[i] = w5[i];
    if (t < 16)  sb[t] = b5[t];
    if (t < 144) sA[t] = Bm[t] + Cm[t];
    if (t < 3)   st[t] = x_tar[t];
    __syncthreads();

    const int b = blockIdx.x * 256 + t;
    float h[64];
    const float* ar = act5 + (size_t)b * 64;
    #pragma unroll
    for (int i = 0; i < 64; ++i) h[i] = ar[i];

    float logit[16];
    float mx = -1e30f;
    #pragma unroll
    for (int n = 0; n < 16; ++n) {
        float s = sb[n];
        const float* wr = sw + n * 64;
        #pragma unroll
        for (int i = 0; i < 64; ++i) s += h[i] * wr[i];
        logit[n] = s;
        mx = fmaxf(mx, s);
    }
    float sum = 0.f;
    #pragma unroll
    for (int n = 0; n < 16; ++n) { logit[n] = __expf(logit[n] - mx); sum += logit[n]; }
    const float inv = 1.f / sum;

    const float d0 = st[0] - x[(size_t)b * XW + 0];
    const float d1 = st[1] - x[(size_t)b * XW + 1];
    const float d2 = st[2] - x[(size_t)b * XW + 2];
    float s0 = 0.f, s1 = 0.f, s2 = 0.f;
    #pragma unroll
    for (int n = 0; n < 16; ++n) {
        const float w = logit[n] * inv;
        const float* An = sA + n * 9;
        s0 += w * (An[0] * d0 + An[1] * d1 + An[2] * d2);
        s1 += w * (An[3] * d0 + An[4] * d1 + An[5] * d2);
        s2 += w * (An[6] * d0 + An[7] * d1 + An[8] * d2);
    }
    out[(size_t)b * 3 + 0] = s0;
    out[(size_t)b * 3 + 1] = s1;
    out[(size_t)b * 3 + 2] = s2;
}

// ---------------------------------------------------------------------------
extern "C" void kernel_launch(void* const* d_in, const int* in_sizes, int n_in,
                              void* d_out, int out_size, void* d_ws, size_t ws_size,
                              hipStream_t stream) {
    const float* x       = (const float*)d_in[0];
    const float* conv1_w = (const float*)d_in[1];
    const float* conv1_b = (const float*)d_in[2];
    const float* conv2_w = (const float*)d_in[3];
    const float* conv2_b = (const float*)d_in[4];
    const float* fc1_w   = (const float*)d_in[5];
    const float* fc1_b   = (const float*)d_in[6];
    const float* fc2_w   = (const float*)d_in[7];
    const float* fc2_b   = (const float*)d_in[8];
    const float* fc3_w   = (const float*)d_in[9];
    const float* fc3_b   = (const float*)d_in[10];
    const float* fc4_w   = (const float*)d_in[11];
    const float* fc4_b   = (const float*)d_in[12];
    const float* fc5_w   = (const float*)d_in[13];
    const float* fc5_b   = (const float*)d_in[14];
    const float* B_mats  = (const float*)d_in[15];
    const float* C_mats  = (const float*)d_in[16];
    const float* x_tar   = (const float*)d_in[17];
    float* out = (float*)d_out;

    char* p = (char*)d_ws;
    short* act1 = (short*)p;  p += (size_t)BSZ * KP1 * 2;   // f16 [8192][1696]
    short* act2 = (short*)p;  p += (size_t)BSZ * 512 * 2;   // f16 [8192][512]
    short* act3 = (short*)p;  p += (size_t)BSZ * 256 * 2;   // f16 [8192][256]
    short* act4 = (short*)p;  p += (size_t)BSZ * 128 * 2;   // f16 [8192][128]
    float* act5 = (float*)p;  p += (size_t)BSZ * 64 * 4;    // f32 [8192][64]
    short* w1h  = (short*)p;  p += (size_t)512 * KP1 * 2;   // f16 [512][1696]
    short* w2h  = (short*)p;  p += (size_t)256 * 512 * 2;   // f16 [256][512]
    short* w3h  = (short*)p;  p += (size_t)128 * 256 * 2;   // f16 [128][256]
    short* w4h  = (short*)p;  p += (size_t)64 * 128 * 2;    // f16 [64][128]

    cvt_all<<<(C3 + 255) / 256, 256, 0, stream>>>(
        fc1_w, w1h, fc2_w, w2h, fc3_w, w3h, fc4_w, w4h);

    conv_fused<<<BSZ, 256, 0, stream>>>(x, conv1_w, conv1_b, conv2_w, conv2_b, act1);

    mfma_fc<1, 1><<<dim3(512 / 64, BSZ / 64), 256, 0, stream>>>(act1, w1h, fc1_b, act2, 512, KP1);
    mfma_fc<1, 1><<<dim3(256 / 64, BSZ / 64), 256, 0, stream>>>(act2, w2h, fc2_b, act3, 256, 512);
    mfma_fc<1, 1><<<dim3(128 / 64, BSZ / 64), 256, 0, stream>>>(act3, w3h, fc3_b, act4, 128, 256);
    mfma_fc<1, 0><<<dim3(64 / 64,  BSZ / 64), 256, 0, stream>>>(act4, w4h, fc4_b, act5, 64, 128);

    head_kernel<<<BSZ / 256, 256, 0, stream>>>(act5, fc5_w, fc5_b, B_mats, C_mats, x, x_tar, out);
}

// Round 17
// 262.141 us; speedup vs baseline: 1.0671x; 1.0671x over previous
//
#include <hip/hip_runtime.h>
#include <hip/hip_bf16.h>
#include <hip/hip_fp16.h>
#include <math.h>

#define XW 4099
#define DSD 3
#define BSZ 8192
#define KP1 1696   // fc1 K padded: 1693 -> 1696 (multiple of 32, 16B-aligned rows)

// conv1 image-copy geometry (bank-spread): row stride 168 B (10 banks),
// imgB offset 11456 B (16 banks). 68 rows per copy.
#define IMGSTRIDE 168
#define IMGB_OFF  11456
#define IMG_BYTES (IMGB_OFF + 68 * IMGSTRIDE)   // 22880 B

typedef __attribute__((ext_vector_type(8))) _Float16 f16x8;
typedef __attribute__((ext_vector_type(4))) float    f32x4;

static __device__ __forceinline__ short f2h(float f) {
    union { _Float16 h; short s; } u;
    u.h = (_Float16)f;
    return u.s;
}

// ---------------------------------------------------------------------------
// Kernel 0: ALL weight conversions in one launch.
// ---------------------------------------------------------------------------
#define C0 (512 * KP1)
#define C1 (C0 + 256 * 512)
#define C2 (C1 + 128 * 256)
#define C3 (C2 + 64 * 128)
__global__ __launch_bounds__(256) void cvt_all(
    const float* __restrict__ w1s, short* __restrict__ w1d,
    const float* __restrict__ w2s, short* __restrict__ w2d,
    const float* __restrict__ w3s, short* __restrict__ w3d,
    const float* __restrict__ w4s, short* __restrict__ w4d)
{
    const int i = blockIdx.x * 256 + threadIdx.x;
    if (i < C0) {
        const int n = i / KP1, k = i % KP1;
        w1d[i] = (k < 1693) ? f2h(w1s[(size_t)n * 1693 + k]) : (short)0;
    } else if (i < C1) {
        const int j = i - C0; w2d[j] = f2h(w2s[j]);
    } else if (i < C2) {
        const int j = i - C1; w3d[j] = f2h(w3s[j]);
    } else if (i < C3) {
        const int j = i - C2; w4d[j] = f2h(w4s[j]);
    }
}

// ---------------------------------------------------------------------------
// Kernel 1: fused conv — BOTH convs on MFMA (r16 verified mapping).
// NEW vs r16: bank-spread image strides. Row stride 168 B (== 10 banks mod
// 32) and imgB at +11456 B (== 16 banks), so lane bits (wa,dy,dx,kg) map to
// banks {0..3}+{0,10}+{0,16}+{0,10,20,30} -> ~2-way aliasing (free) instead
// of the ~4-way conflicts of the 136 B / 9248 B layout. tt-loop unrolled x2
// so 16 gathers are in flight per wait.
// ---------------------------------------------------------------------------
__global__ __launch_bounds__(256, 4) void conv_fused(
    const float* __restrict__ x,
    const float* __restrict__ w1, const float* __restrict__ b1,
    const float* __restrict__ w2, const float* __restrict__ b2,
    short* __restrict__ act1)
{
    __shared__ __align__(16) char smem0[IMG_BYTES];     // imgA/imgB; w2f aliases
    char* imgA = smem0;
    char* imgB = smem0 + IMGB_OFF;
    _Float16 (*w2f)[232] = (_Float16(*)[232])smem0;

    __shared__ __align__(16) _Float16 h1[30][30][8];    // 14400 B; y-stride 480 B
    __shared__ __align__(16) _Float16 w1f[16][72];      // conv1 B-matrix, row 144 B
    __shared__ float cb1s[16];
    __shared__ float cb2s[16];
    __shared__ __align__(16) int kofft[28];             // conv2 kpos -> byte offset

    const int b = blockIdx.x;
    const int t = threadIdx.x;

    // ---- phase 0: zero imgA/imgB + h1; build w1f and small tables
    {
        uint4* z = (uint4*)smem0;
        const uint4 z4 = {0u, 0u, 0u, 0u};
        #pragma unroll
        for (int i = 0; i < 6; ++i) {
            const int idx = t + 256 * i;
            if (idx < IMG_BYTES / 16) z[idx] = z4;
        }
        uint4* h1z = (uint4*)&h1[0][0][0];
        #pragma unroll
        for (int i = 0; i < 4; ++i) {
            const int idx = t + 256 * i;
            if (idx < 900) h1z[idx] = z4;
        }
    }
    if (t < 128) {   // w1f[ch][k]: ky=(k>>5)*4+((k>>3)&3), kx=k&7
        const int ch = t >> 3, k0 = (t & 7) * 8;
        f16x8 cell;
        #pragma unroll
        for (int j = 0; j < 8; ++j) {
            const int k = k0 + j;
            const int ky = (k >> 5) * 4 + ((k >> 3) & 3);
            const int kx = k & 7;
            cell[j] = (ch < 5 && ky < 5 && kx < 5)
                    ? (_Float16)w1[ch * 25 + ky * 5 + kx] : (_Float16)0.f;
        }
        *(f16x8*)&w1f[ch][k0] = cell;
    }
    if (t >= 128 && t < 144) cb1s[t - 128] = (t - 128 < 5) ? b1[t - 128] : 0.f;
    if (t >= 160 && t < 176) cb2s[t - 160] = (t - 160 < 10) ? b2[t - 160] : 0.f;
    if (t >= 192 && t < 220) {
        const int p = t - 192;
        kofft[p] = (p < 25) ? (p / 5) * 480 + (p % 5) * 16 : 0;
    }
    __syncthreads();

    // ---- stage image: f32 -> f16 dual write (imgB[c] = v(c+1))
    const float* xr = x + (size_t)b * XW + DSD;
    #pragma unroll
    for (int i = 0; i < 16; ++i) {
        const int idx = t + 256 * i;
        const int yy = idx >> 6, xx = idx & 63;
        const _Float16 v = (_Float16)xr[idx];
        *(_Float16*)(imgA + yy * IMGSTRIDE + xx * 2) = v;
        if (xx > 0) *(_Float16*)(imgB + yy * IMGSTRIDE + (xx - 1) * 2) = v;
    }
    __syncthreads();

    // ---- conv1 via MFMA implicit GEMM + in-lane 2x2 pool + relu -> h1
    {
        const int lane = t & 63, wv_ = t >> 6;
        const int lr = lane & 15, kg = lane >> 4;
        const int wa = lr >> 2;                 // A-row's window within tile
        const int dy = lr & 1, dx = (lr >> 1) & 1;
        const f16x8 bf0 = *(const f16x8*)&w1f[lr][kg * 8];
        const f16x8 bf1 = *(const f16x8*)&w1f[lr][32 + kg * 8];
        const char* base0 = dx ? imgB : imgA;
        const float bias1 = cb1s[lr];
        const int r0 = kg * IMGSTRIDE;          // s=0: ky = kg
        const int r1 = (4 + kg) * IMGSTRIDE;    // s=1: ky = 4+kg

        #pragma unroll 2
        for (int tt = wv_; tt < 225; tt += 4) {
            const int w_A = tt * 4 + wa;                 // 0..899
            const int wyA = (w_A * 2185) >> 16;          // /30
            const int wxA = w_A - wyA * 30;
            const char* pb = base0 + (2 * wyA + dy) * IMGSTRIDE + wxA * 4;
            union { f16x8 v; unsigned u[4]; } A0, A1;
            #pragma unroll
            for (int j = 0; j < 4; ++j) A0.u[j] = *(const unsigned*)(pb + r0 + 4 * j);
            #pragma unroll
            for (int j = 0; j < 4; ++j) A1.u[j] = *(const unsigned*)(pb + r1 + 4 * j);
            f32x4 acc = {0.f, 0.f, 0.f, 0.f};
            acc = __builtin_amdgcn_mfma_f32_16x16x32_f16(A0.v, bf0, acc, 0, 0, 0);
            acc = __builtin_amdgcn_mfma_f32_16x16x32_f16(A1.v, bf1, acc, 0, 0, 0);
            if (lr < 5) {
                const int w_C = tt * 4 + kg;
                const int wyC = (w_C * 2185) >> 16;
                const int wxC = w_C - wyC * 30;
                const float m = fmaxf(fmaxf(acc[0], acc[1]), fmaxf(acc[2], acc[3]));
                h1[wyC][wxC][lr] = (_Float16)fmaxf(m + bias1, 0.f);
            }
        }
    }
    __syncthreads();

    // ---- build w2f over the dead img region: 448 cells, 256 threads
    for (int i = t; i < 448; i += 256) {
        const int wc = i / 28, wp = i % 28;
        f16x8 cell;
        #pragma unroll
        for (int ic = 0; ic < 8; ++ic) cell[ic] = (_Float16)0.f;
        if (wc < 10 && wp < 25) {
            #pragma unroll
            for (int ic = 0; ic < 5; ++ic)
                cell[ic] = (_Float16)w2[(wc * 5 + ic) * 25 + wp];
        }
        *(f16x8*)&w2f[wc][wp * 8] = cell;
    }
    __syncthreads();

    // ---- conv2 via MFMA implicit GEMM, wide b128 A-fragments (r15 form)
    short* outr = act1 + (size_t)b * KP1;
    {
        const int wv_ = t >> 6, lane = t & 63;
        const int lr = lane & 15, kg = lane >> 4;
        const float bias2 = cb2s[lr];
        const int qa = lr & 3;
        const int wa_off = lr >> 2;

        int bases[11];
        #pragma unroll
        for (int u = 0; u < 11; ++u) {
            const int tt = u * 4 + wv_;                  // 0..43
            int w_A = tt * 4 + wa_off;                   // 0..175
            w_A = (w_A < 169) ? w_A : 168;               // clamp pad rows
            const int Y = (w_A * 5042) >> 16;            // /13
            const int X = w_A - Y * 13;
            bases[u] = (2 * Y + (qa & 1)) * 480 + (2 * X + (qa >> 1)) * 16;
        }

        f32x4 acc[11];
        #pragma unroll
        for (int u = 0; u < 11; ++u) acc[u] = (f32x4){0.f, 0.f, 0.f, 0.f};

        const char* h1p = (const char*)&h1[0][0][0];

        #pragma unroll 1
        for (int s = 0; s < 7; ++s) {
            const int koffp = kofft[s * 4 + kg];
            const f16x8 bfs = *(const f16x8*)&w2f[lr][s * 32 + kg * 8];
            #pragma unroll
            for (int u = 0; u < 11; ++u) {
                const f16x8 af = *(const f16x8*)(h1p + (bases[u] + koffp));
                acc[u] = __builtin_amdgcn_mfma_f32_16x16x32_f16(af, bfs, acc[u], 0, 0, 0);
            }
        }

        #pragma unroll
        for (int u = 0; u < 11; ++u) {
            const int tt = u * 4 + wv_;
            const int w_C = tt * 4 + kg;
            if (lr < 10 && w_C < 169) {
                const float m = fmaxf(fmaxf(acc[u][0], acc[u][1]), fmaxf(acc[u][2], acc[u][3]));
                outr[lr * 169 + w_C] = f2h(fmaxf(m + bias2, 0.f));
            }
        }
    }
    if (t < DSD)           outr[1690 + t] = f2h(x[(size_t)b * XW + t]);
    if (t >= DSD && t < 6) outr[1690 + t] = 0;   // zero pad 1693..1695
}

// ---------------------------------------------------------------------------
// Kernel 2: MFMA fp16 GEMM, 64x64 tile, BK=32 (r12-validated form)
// ---------------------------------------------------------------------------
template <int RELU, int OUTH>
__global__ __launch_bounds__(256) void mfma_fc(
    const short* __restrict__ A, const short* __restrict__ W,
    const float* __restrict__ bias, void* __restrict__ Cout,
    int N, int Kp)
{
    __shared__ __align__(16) short As[64][40];
    __shared__ __align__(16) short Ws[64][40];

    const int tid  = threadIdx.x;
    const int m0   = blockIdx.y * 64;
    const int n0   = blockIdx.x * 64;
    const int wv   = tid >> 6, lane = tid & 63;
    const int rm   = (wv >> 1) * 32, rn = (wv & 1) * 32;
    const int lr   = lane & 15, kg = lane >> 4;
    const int sr   = tid >> 2, sc = (tid & 3) * 8;

    f32x4 acc[2][2];
    #pragma unroll
    for (int i = 0; i < 2; ++i)
        #pragma unroll
        for (int j = 0; j < 2; ++j)
            #pragma unroll
            for (int q = 0; q < 4; ++q) acc[i][j][q] = 0.f;

    for (int k0 = 0; k0 < Kp; k0 += 32) {
        *(uint4*)&As[sr][sc] = *(const uint4*)&A[(size_t)(m0 + sr) * Kp + k0 + sc];
        *(uint4*)&Ws[sr][sc] = *(const uint4*)&W[(size_t)(n0 + sr) * Kp + k0 + sc];
        __syncthreads();
        f16x8 aF[2], bF[2];
        #pragma unroll
        for (int mi = 0; mi < 2; ++mi) aF[mi] = *(const f16x8*)&As[rm + mi * 16 + lr][kg * 8];
        #pragma unroll
        for (int nj = 0; nj < 2; ++nj) bF[nj] = *(const f16x8*)&Ws[rn + nj * 16 + lr][kg * 8];
        #pragma unroll
        for (int mi = 0; mi < 2; ++mi)
            #pragma unroll
            for (int nj = 0; nj < 2; ++nj)
                acc[mi][nj] = __builtin_amdgcn_mfma_f32_16x16x32_f16(
                    aF[mi], bF[nj], acc[mi][nj], 0, 0, 0);
        __syncthreads();
    }

    #pragma unroll
    for (int mi = 0; mi < 2; ++mi)
        #pragma unroll
        for (int nj = 0; nj < 2; ++nj) {
            const int col  = n0 + rn + nj * 16 + lr;
            const int rowb = m0 + rm + mi * 16 + kg * 4;
            const float bv = bias[col];
            #pragma unroll
            for (int q = 0; q < 4; ++q) {
                float v = acc[mi][nj][q] + bv;
                if (RELU) v = fmaxf(v, 0.f);
                if (OUTH) ((short*)Cout)[(size_t)(rowb + q) * N + col] = f2h(v);
                else      ((float*)Cout)[(size_t)(rowb + q) * N + col] = v;
            }
        }
}

// ---------------------------------------------------------------------------
// Kernel 4: fc5 + softmax + expert combine -> out[B,3]
// ---------------------------------------------------------------------------
__global__ __launch_bounds__(256) void head_kernel(
    const float* __restrict__ act5, const float* __restrict__ w5,
    const float* __restrict__ b5, const float* __restrict__ Bm,
    const float* __restrict__ Cm, const float* __restrict__ x,
    const float* __restrict__ x_tar, float* __restrict__ out)
{
    __shared__ float sw[16 * 64];
    __shared__ float sb[16];
    __shared__ float sA[16 * 9];
    __shared__ float st[3];
    const int t = threadIdx.x;
    for (int i = t; i < 1024; i += 256) sw[i] = w5[i];
    if (t < 16)  sb[t] = b5[t];
    if (t < 144) sA[t] = Bm[t] + Cm[t];
    if (t < 3)   st[t] = x_tar[t];
    __syncthreads();

    const int b = blockIdx.x * 256 + t;
    float h[64];
    const float* ar = act5 + (size_t)b * 64;
    #pragma unroll
    for (int i = 0; i < 64; ++i) h[i] = ar[i];

    float logit[16];
    float mx = -1e30f;
    #pragma unroll
    for (int n = 0; n < 16; ++n) {
        float s = sb[n];
        const float* wr = sw + n * 64;
        #pragma unroll
        for (int i = 0; i < 64; ++i) s += h[i] * wr[i];
        logit[n] = s;
        mx = fmaxf(mx, s);
    }
    float sum = 0.f;
    #pragma unroll
    for (int n = 0; n < 16; ++n) { logit[n] = __expf(logit[n] - mx); sum += logit[n]; }
    const float inv = 1.f / sum;

    const float d0 = st[0] - x[(size_t)b * XW + 0];
    const float d1 = st[1] - x[(size_t)b * XW + 1];
    const float d2 = st[2] - x[(size_t)b * XW + 2];
    float s0 = 0.f, s1 = 0.f, s2 = 0.f;
    #pragma unroll
    for (int n = 0; n < 16; ++n) {
        const float w = logit[n] * inv;
        const float* An = sA + n * 9;
        s0 += w * (An[0] * d0 + An[1] * d1 + An[2] * d2);
        s1 += w * (An[3] * d0 + An[4] * d1 + An[5] * d2);
        s2 += w * (An[6] * d0 + An[7] * d1 + An[8] * d2);
    }
    out[(size_t)b * 3 + 0] = s0;
    out[(size_t)b * 3 + 1] = s1;
    out[(size_t)b * 3 + 2] = s2;
}

// ---------------------------------------------------------------------------
extern "C" void kernel_launch(void* const* d_in, const int* in_sizes, int n_in,
                              void* d_out, int out_size, void* d_ws, size_t ws_size,
                              hipStream_t stream) {
    const float* x       = (const float*)d_in[0];
    const float* conv1_w = (const float*)d_in[1];
    const float* conv1_b = (const float*)d_in[2];
    const float* conv2_w = (const float*)d_in[3];
    const float* conv2_b = (const float*)d_in[4];
    const float* fc1_w   = (const float*)d_in[5];
    const float* fc1_b   = (const float*)d_in[6];
    const float* fc2_w   = (const float*)d_in[7];
    const float* fc2_b   = (const float*)d_in[8];
    const float* fc3_w   = (const float*)d_in[9];
    const float* fc3_b   = (const float*)d_in[10];
    const float* fc4_w   = (const float*)d_in[11];
    const float* fc4_b   = (const float*)d_in[12];
    const float* fc5_w   = (const float*)d_in[13];
    const float* fc5_b   = (const float*)d_in[14];
    const float* B_mats  = (const float*)d_in[15];
    const float* C_mats  = (const float*)d_in[16];
    const float* x_tar   = (const float*)d_in[17];
    float* out = (float*)d_out;

    char* p = (char*)d_ws;
    short* act1 = (short*)p;  p += (size_t)BSZ * KP1 * 2;   // f16 [8192][1696]
    short* act2 = (short*)p;  p += (size_t)BSZ * 512 * 2;   // f16 [8192][512]
    short* act3 = (short*)p;  p += (size_t)BSZ * 256 * 2;   // f16 [8192][256]
    short* act4 = (short*)p;  p += (size_t)BSZ * 128 * 2;   // f16 [8192][128]
    float* act5 = (float*)p;  p += (size_t)BSZ * 64 * 4;    // f32 [8192][64]
    short* w1h  = (short*)p;  p += (size_t)512 * KP1 * 2;   // f16 [512][1696]
    short* w2h  = (short*)p;  p += (size_t)256 * 512 * 2;   // f16 [256][512]
    short* w3h  = (short*)p;  p += (size_t)128 * 256 * 2;   // f16 [128][256]
    short* w4h  = (short*)p;  p += (size_t)64 * 128 * 2;    // f16 [64][128]

    cvt_all<<<(C3 + 255) / 256, 256, 0, stream>>>(
        fc1_w, w1h, fc2_w, w2h, fc3_w, w3h, fc4_w, w4h);

    conv_fused<<<BSZ, 256, 0, stream>>>(x, conv1_w, conv1_b, conv2_w, conv2_b, act1);

    mfma_fc<1, 1><<<dim3(512 / 64, BSZ / 64), 256, 0, stream>>>(act1, w1h, fc1_b, act2, 512, KP1);
    mfma_fc<1, 1><<<dim3(256 / 64, BSZ / 64), 256, 0, stream>>>(act2, w2h, fc2_b, act3, 256, 512);
    mfma_fc<1, 1><<<dim3(128 / 64, BSZ / 64), 256, 0, stream>>>(act3, w3h, fc3_b, act4, 128, 256);
    mfma_fc<1, 0><<<dim3(64 / 64,  BSZ / 64), 256, 0, stream>>>(act4, w4h, fc4_b, act5, 64, 128);

    head_kernel<<<BSZ / 256, 256, 0, stream>>>(act5, fc5_w, fc5_b, B_mats, C_mats, x, x_tar, out);
}

// Round 18
// 211.091 us; speedup vs baseline: 1.3252x; 1.2418x over previous
//
#include <hip/hip_runtime.h>
#include <hip/hip_bf16.h>
#include <hip/hip_fp16.h>
#include <math.h>

#define XW 4099
#define DSD 3
#define BSZ 8192
#define KP1 1696   // fc1 K padded: 1693 -> 1696 (multiple of 32, 16B-aligned rows)

typedef __attribute__((ext_vector_type(8))) _Float16 f16x8;
typedef __attribute__((ext_vector_type(4))) float    f32x4;

static __device__ __forceinline__ short f2h(float f) {
    union { _Float16 h; short s; } u;
    u.h = (_Float16)f;
    return u.s;
}

// ---------------------------------------------------------------------------
// Kernel 0: ALL weight conversions in one launch (w1 padded 1693->1696;
// w2..w4 have K==Kp, direct convert).
// ---------------------------------------------------------------------------
#define C0 (512 * KP1)
#define C1 (C0 + 256 * 512)
#define C2 (C1 + 128 * 256)
#define C3 (C2 + 64 * 128)
__global__ __launch_bounds__(256) void cvt_all(
    const float* __restrict__ w1s, short* __restrict__ w1d,
    const float* __restrict__ w2s, short* __restrict__ w2d,
    const float* __restrict__ w3s, short* __restrict__ w3d,
    const float* __restrict__ w4s, short* __restrict__ w4d)
{
    const int i = blockIdx.x * 256 + threadIdx.x;
    if (i < C0) {
        const int n = i / KP1, k = i % KP1;
        w1d[i] = (k < 1693) ? f2h(w1s[(size_t)n * 1693 + k]) : (short)0;
    } else if (i < C1) {
        const int j = i - C0; w2d[j] = f2h(w2s[j]);
    } else if (i < C2) {
        const int j = i - C1; w3d[j] = f2h(w3s[j]);
    } else if (i < C3) {
        const int j = i - C2; w4d[j] = f2h(w4s[j]);
    }
}

// ---------------------------------------------------------------------------
// Kernel 1: fused conv (r15-validated form, best measured: conv ~163 us).
// conv1 = f32 VALU 4x4-region tiles (patch 16x ds_read_b128, weights via
// LDS broadcast); conv2 = MFMA implicit GEMM with channel-innermost h1
// ([y][x][ic-pad8], K''=kpos*8+ic) and wide b128 A-fragments.
// ---------------------------------------------------------------------------
__global__ __launch_bounds__(256, 4) void conv_fused(
    const float* __restrict__ x,
    const float* __restrict__ w1, const float* __restrict__ b1,
    const float* __restrict__ w2, const float* __restrict__ b2,
    short* __restrict__ act1)
{
    // img [64][68] f32 (17408 B) aliased with w2f [16][232] f16 (7424 B)
    __shared__ __align__(16) char smem0[64 * 68 * 4];
    float     (*img)[68]  = (float(*)[68])smem0;
    _Float16  (*w2f)[232] = (_Float16(*)[232])smem0;

    __shared__ __align__(16) _Float16  h1[30][30][8];   // 14400 B; y-stride 480 B
    __shared__ __align__(16) float     cw1[5][28];      // conv1 w, padded for f32x4
    __shared__ float cb1[5];
    __shared__ float cb2s[16];
    __shared__ __align__(16) int kofft[28];             // kpos -> byte offset into h1

    const int b = blockIdx.x;
    const int t = threadIdx.x;

    // ---- phase 0: stage img + zero h1 + small tables
    const float* xr = x + (size_t)b * XW + DSD;
    #pragma unroll
    for (int i = 0; i < 16; ++i) {
        const int idx = t + 256 * i;
        img[idx >> 6][idx & 63] = xr[idx];
    }
    {   // zero h1 entirely (ic pads 5..7 MUST be 0 for the MFMA)
        uint4* h1z = (uint4*)&h1[0][0][0];
        const uint4 z4 = {0u, 0u, 0u, 0u};
        #pragma unroll
        for (int i = 0; i < 4; ++i) {
            const int idx = t + 256 * i;
            if (idx < 900) h1z[idx] = z4;
        }
    }
    if (t < 140) { const int c = t / 28, k = t % 28; cw1[c][k] = (k < 25) ? w1[c * 25 + k] : 0.f; }
    if (t >= 144 && t < 149) cb1[t - 144] = b1[t - 144];
    if (t >= 160 && t < 176) cb2s[t - 160] = (t - 160 < 10) ? b2[t - 160] : 0.f;
    if (t >= 192 && t < 220) {
        const int p = t - 192;
        kofft[p] = (p < 25) ? (p / 5) * 480 + (p % 5) * 16 : 0;
    }
    __syncthreads();

    // ---- conv1 + relu + pool (f32 VALU): 15x15 tiles of 2x2 pooled
    if (t < 225) {
        const int ty = t / 15, tx = t % 15;
        const int y0 = 4 * ty, x0 = 4 * tx;
        f32x4 pv[8][2];
        #pragma unroll
        for (int r = 0; r < 8; ++r) {
            pv[r][0] = *(const f32x4*)&img[y0 + r][x0];
            pv[r][1] = *(const f32x4*)&img[y0 + r][x0 + 4];
        }
        asm volatile("" :
            "+v"(pv[0][0]), "+v"(pv[0][1]), "+v"(pv[1][0]), "+v"(pv[1][1]),
            "+v"(pv[2][0]), "+v"(pv[2][1]), "+v"(pv[3][0]), "+v"(pv[3][1]),
            "+v"(pv[4][0]), "+v"(pv[4][1]), "+v"(pv[5][0]), "+v"(pv[5][1]),
            "+v"(pv[6][0]), "+v"(pv[6][1]), "+v"(pv[7][0]), "+v"(pv[7][1]));
        #pragma unroll 1
        for (int c = 0; c < 5; ++c) {
            f32x4 wv4[7];
            #pragma unroll
            for (int i = 0; i < 7; ++i) wv4[i] = *(const f32x4*)&cw1[c][4 * i];
            const float bias = cb1[c];
            float acc[4][4];
            #pragma unroll
            for (int cy = 0; cy < 4; ++cy)
                #pragma unroll
                for (int cx = 0; cx < 4; ++cx) acc[cy][cx] = bias;
            #pragma unroll
            for (int ky = 0; ky < 5; ++ky)
                #pragma unroll
                for (int kx = 0; kx < 5; ++kx) {
                    const int kk = ky * 5 + kx;
                    const float wv = wv4[kk >> 2][kk & 3];
                    #pragma unroll
                    for (int cy = 0; cy < 4; ++cy)
                        #pragma unroll
                        for (int cx = 0; cx < 4; ++cx) {
                            const int px = cx + kx;
                            acc[cy][cx] += pv[cy + ky][px >> 2][px & 3] * wv;
                        }
                }
            #pragma unroll
            for (int sy = 0; sy < 2; ++sy)
                #pragma unroll
                for (int sx = 0; sx < 2; ++sx) {
                    const float m = fmaxf(
                        fmaxf(acc[2 * sy][2 * sx],     acc[2 * sy][2 * sx + 1]),
                        fmaxf(acc[2 * sy + 1][2 * sx], acc[2 * sy + 1][2 * sx + 1]));
                    h1[2 * ty + sy][2 * tx + sx][c] = (_Float16)fmaxf(m, 0.f);
                }
        }
    }
    __syncthreads();

    // ---- build w2f over the dead img region: ALL 448 cells, 256 threads
    for (int i = t; i < 448; i += 256) {
        const int wc = i / 28, wp = i % 28;
        f16x8 cell;
        #pragma unroll
        for (int ic = 0; ic < 8; ++ic) cell[ic] = (_Float16)0.f;
        if (wc < 10 && wp < 25) {
            #pragma unroll
            for (int ic = 0; ic < 5; ++ic)
                cell[ic] = (_Float16)w2[(wc * 5 + ic) * 25 + wp];
        }
        *(f16x8*)&w2f[wc][wp * 8] = cell;
    }
    __syncthreads();

    // ---- conv2 via MFMA implicit GEMM, wide b128 A-fragments
    short* outr = act1 + (size_t)b * KP1;
    {
        const int wv_ = t >> 6, lane = t & 63;
        const int lr = lane & 15, kg = lane >> 4;
        const float bias2 = cb2s[lr];
        const int qa = lr & 3;          // pool-window element of this A-row
        const int wa_off = lr >> 2;     // window within tile for A-row

        int bases[11];
        #pragma unroll
        for (int u = 0; u < 11; ++u) {
            const int tt = u * 4 + wv_;                  // 0..43
            int w_A = tt * 4 + wa_off;                   // 0..175
            w_A = (w_A < 169) ? w_A : 168;               // clamp pad rows (D discarded)
            const int Y = (w_A * 5042) >> 16;            // w_A / 13
            const int X = w_A - Y * 13;
            bases[u] = (2 * Y + (qa & 1)) * 480 + (2 * X + (qa >> 1)) * 16;
        }

        f32x4 acc[11];
        #pragma unroll
        for (int u = 0; u < 11; ++u) acc[u] = (f32x4){0.f, 0.f, 0.f, 0.f};

        const char* h1p = (const char*)&h1[0][0][0];

        #pragma unroll 1
        for (int s = 0; s < 7; ++s) {
            const int koffp = kofft[s * 4 + kg];         // broadcast per kg group
            const f16x8 bfs = *(const f16x8*)&w2f[lr][s * 32 + kg * 8];
            #pragma unroll
            for (int u = 0; u < 11; ++u) {
                const f16x8 af = *(const f16x8*)(h1p + (bases[u] + koffp));
                acc[u] = __builtin_amdgcn_mfma_f32_16x16x32_f16(af, bfs, acc[u], 0, 0, 0);
            }
        }

        #pragma unroll
        for (int u = 0; u < 11; ++u) {
            const int tt = u * 4 + wv_;
            const int w_C = tt * 4 + kg;
            if (lr < 10 && w_C < 169) {
                const float m = fmaxf(fmaxf(acc[u][0], acc[u][1]), fmaxf(acc[u][2], acc[u][3]));
                outr[lr * 169 + w_C] = f2h(fmaxf(m + bias2, 0.f));
            }
        }
    }
    if (t < DSD)           outr[1690 + t] = f2h(x[(size_t)b * XW + t]);
    if (t >= DSD && t < 6) outr[1690 + t] = 0;   // zero pad 1693..1695
}

// ---------------------------------------------------------------------------
// Kernel 2: MFMA fp16 GEMM, 64x64 tile, BK=32 (r12-validated form)
// ---------------------------------------------------------------------------
template <int RELU, int OUTH>
__global__ __launch_bounds__(256) void mfma_fc(
    const short* __restrict__ A, const short* __restrict__ W,
    const float* __restrict__ bias, void* __restrict__ Cout,
    int N, int Kp)
{
    __shared__ __align__(16) short As[64][40];
    __shared__ __align__(16) short Ws[64][40];

    const int tid  = threadIdx.x;
    const int m0   = blockIdx.y * 64;
    const int n0   = blockIdx.x * 64;
    const int wv   = tid >> 6, lane = tid & 63;
    const int rm   = (wv >> 1) * 32, rn = (wv & 1) * 32;
    const int lr   = lane & 15, kg = lane >> 4;
    const int sr   = tid >> 2, sc = (tid & 3) * 8;

    f32x4 acc[2][2];
    #pragma unroll
    for (int i = 0; i < 2; ++i)
        #pragma unroll
        for (int j = 0; j < 2; ++j)
            #pragma unroll
            for (int q = 0; q < 4; ++q) acc[i][j][q] = 0.f;

    for (int k0 = 0; k0 < Kp; k0 += 32) {
        *(uint4*)&As[sr][sc] = *(const uint4*)&A[(size_t)(m0 + sr) * Kp + k0 + sc];
        *(uint4*)&Ws[sr][sc] = *(const uint4*)&W[(size_t)(n0 + sr) * Kp + k0 + sc];
        __syncthreads();
        f16x8 aF[2], bF[2];
        #pragma unroll
        for (int mi = 0; mi < 2; ++mi) aF[mi] = *(const f16x8*)&As[rm + mi * 16 + lr][kg * 8];
        #pragma unroll
        for (int nj = 0; nj < 2; ++nj) bF[nj] = *(const f16x8*)&Ws[rn + nj * 16 + lr][kg * 8];
        #pragma unroll
        for (int mi = 0; mi < 2; ++mi)
            #pragma unroll
            for (int nj = 0; nj < 2; ++nj)
                acc[mi][nj] = __builtin_amdgcn_mfma_f32_16x16x32_f16(
                    aF[mi], bF[nj], acc[mi][nj], 0, 0, 0);
        __syncthreads();
    }

    #pragma unroll
    for (int mi = 0; mi < 2; ++mi)
        #pragma unroll
        for (int nj = 0; nj < 2; ++nj) {
            const int col  = n0 + rn + nj * 16 + lr;
            const int rowb = m0 + rm + mi * 16 + kg * 4;
            const float bv = bias[col];
            #pragma unroll
            for (int q = 0; q < 4; ++q) {
                float v = acc[mi][nj][q] + bv;
                if (RELU) v = fmaxf(v, 0.f);
                if (OUTH) ((short*)Cout)[(size_t)(rowb + q) * N + col] = f2h(v);
                else      ((float*)Cout)[(size_t)(rowb + q) * N + col] = v;
            }
        }
}

// ---------------------------------------------------------------------------
// Kernel 4: fc5 + softmax + expert combine -> out[B,3]
// ---------------------------------------------------------------------------
__global__ __launch_bounds__(256) void head_kernel(
    const float* __restrict__ act5, const float* __restrict__ w5,
    const float* __restrict__ b5, const float* __restrict__ Bm,
    const float* __restrict__ Cm, const float* __restrict__ x,
    const float* __restrict__ x_tar, float* __restrict__ out)
{
    __shared__ float sw[16 * 64];
    __shared__ float sb[16];
    __shared__ float sA[16 * 9];
    __shared__ float st[3];
    const int t = threadIdx.x;
    for (int i = t; i < 1024; i += 256) sw[i] = w5[i];
    if (t < 16)  sb[t] = b5[t];
    if (t < 144) sA[t] = Bm[t] + Cm[t];
    if (t < 3)   st[t] = x_tar[t];
    __syncthreads();

    const int b = blockIdx.x * 256 + t;
    float h[64];
    const float* ar = act5 + (size_t)b * 64;
    #pragma unroll
    for (int i = 0; i < 64; ++i) h[i] = ar[i];

    float logit[16];
    float mx = -1e30f;
    #pragma unroll
    for (int n = 0; n < 16; ++n) {
        float s = sb[n];
        const float* wr = sw + n * 64;
        #pragma unroll
        for (int i = 0; i < 64; ++i) s += h[i] * wr[i];
        logit[n] = s;
        mx = fmaxf(mx, s);
    }
    float sum = 0.f;
    #pragma unroll
    for (int n = 0; n < 16; ++n) { logit[n] = __expf(logit[n] - mx); sum += logit[n]; }
    const float inv = 1.f / sum;

    const float d0 = st[0] - x[(size_t)b * XW + 0];
    const float d1 = st[1] - x[(size_t)b * XW + 1];
    const float d2 = st[2] - x[(size_t)b * XW + 2];
    float s0 = 0.f, s1 = 0.f, s2 = 0.f;
    #pragma unroll
    for (int n = 0; n < 16; ++n) {
        const float w = logit[n] * inv;
        const float* An = sA + n * 9;
        s0 += w * (An[0] * d0 + An[1] * d1 + An[2] * d2);
        s1 += w * (An[3] * d0 + An[4] * d1 + An[5] * d2);
        s2 += w * (An[6] * d0 + An[7] * d1 + An[8] * d2);
    }
    out[(size_t)b * 3 + 0] = s0;
    out[(size_t)b * 3 + 1] = s1;
    out[(size_t)b * 3 + 2] = s2;
}

// ---------------------------------------------------------------------------
extern "C" void kernel_launch(void* const* d_in, const int* in_sizes, int n_in,
                              void* d_out, int out_size, void* d_ws, size_t ws_size,
                              hipStream_t stream) {
    const float* x       = (const float*)d_in[0];
    const float* conv1_w = (const float*)d_in[1];
    const float* conv1_b = (const float*)d_in[2];
    const float* conv2_w = (const float*)d_in[3];
    const float* conv2_b = (const float*)d_in[4];
    const float* fc1_w   = (const float*)d_in[5];
    const float* fc1_b   = (const float*)d_in[6];
    const float* fc2_w   = (const float*)d_in[7];
    const float* fc2_b   = (const float*)d_in[8];
    const float* fc3_w   = (const float*)d_in[9];
    const float* fc3_b   = (const float*)d_in[10];
    const float* fc4_w   = (const float*)d_in[11];
    const float* fc4_b   = (const float*)d_in[12];
    const float* fc5_w   = (const float*)d_in[13];
    const float* fc5_b   = (const float*)d_in[14];
    const float* B_mats  = (const float*)d_in[15];
    const float* C_mats  = (const float*)d_in[16];
    const float* x_tar   = (const float*)d_in[17];
    float* out = (float*)d_out;

    char* p = (char*)d_ws;
    short* act1 = (short*)p;  p += (size_t)BSZ * KP1 * 2;   // f16 [8192][1696]
    short* act2 = (short*)p;  p += (size_t)BSZ * 512 * 2;   // f16 [8192][512]
    short* act3 = (short*)p;  p += (size_t)BSZ * 256 * 2;   // f16 [8192][256]
    short* act4 = (short*)p;  p += (size_t)BSZ * 128 * 2;   // f16 [8192][128]
    float* act5 = (float*)p;  p += (size_t)BSZ * 64 * 4;    // f32 [8192][64]
    short* w1h  = (short*)p;  p += (size_t)512 * KP1 * 2;   // f16 [512][1696]
    short* w2h  = (short*)p;  p += (size_t)256 * 512 * 2;   // f16 [256][512]
    short* w3h  = (short*)p;  p += (size_t)128 * 256 * 2;   // f16 [128][256]
    short* w4h  = (short*)p;  p += (size_t)64 * 128 * 2;    // f16 [64][128]

    cvt_all<<<(C3 + 255) / 256, 256, 0, stream>>>(
        fc1_w, w1h, fc2_w, w2h, fc3_w, w3h, fc4_w, w4h);

    conv_fused<<<BSZ, 256, 0, stream>>>(x, conv1_w, conv1_b, conv2_w, conv2_b, act1);

    mfma_fc<1, 1><<<dim3(512 / 64, BSZ / 64), 256, 0, stream>>>(act1, w1h, fc1_b, act2, 512, KP1);
    mfma_fc<1, 1><<<dim3(256 / 64, BSZ / 64), 256, 0, stream>>>(act2, w2h, fc2_b, act3, 256, 512);
    mfma_fc<1, 1><<<dim3(128 / 64, BSZ / 64), 256, 0, stream>>>(act3, w3h, fc3_b, act4, 128, 256);
    mfma_fc<1, 0><<<dim3(64 / 64,  BSZ / 64), 256, 0, stream>>>(act4, w4h, fc4_b, act5, 64, 128);

    head_kernel<<<BSZ / 256, 256, 0, stream>>>(act5, fc5_w, fc5_b, B_mats, C_mats, x, x_tar, out);
}